// Round 13
// baseline (103.319 us; speedup 1.0000x reference)
//
#include <hip/hip_runtime.h>

typedef _Float16 f16;
typedef _Float16 f16x4 __attribute__((ext_vector_type(4)));
typedef _Float16 f16x8 __attribute__((ext_vector_type(8)));
typedef float    f32x4 __attribute__((ext_vector_type(4)));

#define MFMA(A,B,C) __builtin_amdgcn_mfma_f32_16x16x32_f16((A),(B),(C),0,0,0)

// sigmoid on pre-scaled input y = x*log2(e): 1/(1+2^-y)
__device__ __forceinline__ float sig2(float y) {
    return __builtin_amdgcn_rcpf(1.0f + __builtin_amdgcn_exp2f(-y));
}

constexpr float L2E  = 1.4426950408889634f;
constexpr float L2E2 = 2.8853900817779268f;

constexpr int STR = 72;   // ABUF row stride (f16): cols 0..63 act | 64..68 x | 69 = 1.0 | 70..71 = 0

// d_ws fragment-layout offsets (f16 elems); all [kt][n][8] with elem = (kt*N + n)*8 + j
constexpr int OFF_WG = 0;          // [9][256][8]  gates (prescaled, bias at k=69); kb8 read from HERE (global)
constexpr int OFF_W1 = 18432;      // [8][256][8]
constexpr int OFF_W2 = 34816;      // [32][64][8]
constexpr int OFF_W3 = 51200;      // [8][32][8]
constexpr int OFF_W4 = 53248;      // [4][16][8]
constexpr int OFF_WH = 53760;      // [4][16][8] (zero-padded k>=16, n>=3)
constexpr int OFF_Z  = 54272;      // 2560 f16 zeros (B-side zero frags for hi>0 lanes)
constexpr int WS_TOT = 56832;

// ---------------- prep kernel: build f16 fragment buffers in d_ws ----------------
__global__ void wprep(const float* __restrict__ Wih, const float* __restrict__ Whh,
                      const float* __restrict__ bih, const float* __restrict__ bhh,
                      const float* __restrict__ w1p, const float* __restrict__ w2p,
                      const float* __restrict__ w3p, const float* __restrict__ w4p,
                      const float* __restrict__ whp, f16* __restrict__ ws) {
    int idx = blockIdx.x * 256 + threadIdx.x;
    if (idx >= WS_TOT) return;
    float v = 0.0f;
    if (idx < OFF_W1) {                       // gates, prescaled by L2E (i,f,o) / 2*L2E (g)
        int r = idx, kb = r >> 11, n = (r >> 3) & 255, j = r & 7;
        float sc = (n >= 128 && n < 192) ? L2E2 : L2E;
        if (kb < 8)      v = Whh[n * 64 + kb * 8 + j];
        else if (j < 5)  v = Wih[n * 5 + j];
        else if (j == 5) v = bih[n] + bhh[n];
        v *= sc;
    } else if (idx < OFF_W2) {
        int r = idx - OFF_W1, kt = r >> 11, n = (r >> 3) & 255, j = r & 7;
        v = w1p[n * 64 + kt * 8 + j];
    } else if (idx < OFF_W3) {
        int r = idx - OFF_W2, kt = r >> 9, n = (r >> 3) & 63, j = r & 7;
        v = w2p[n * 256 + kt * 8 + j];
    } else if (idx < OFF_W4) {
        int r = idx - OFF_W3, kt = r >> 8, n = (r >> 3) & 31, j = r & 7;
        v = w3p[n * 64 + kt * 8 + j];
    } else if (idx < OFF_WH) {
        int r = idx - OFF_W4, kt = r >> 7, n = (r >> 3) & 15, j = r & 7;
        v = w4p[n * 32 + kt * 8 + j];
    } else if (idx < OFF_Z) {
        int r = idx - OFF_WH, kt = r >> 7, n = (r >> 3) & 15, j = r & 7;
        int k = kt * 8 + j;
        v = (k < 16 && n < 3) ? whp[n * 16 + k] : 0.0f;
    } // else: zero region
    ws[idx] = (f16)v;
}

// ---------------- main kernel ----------------
// R12 (best, 86us): 16-row tiles, no spill, VGPR 60 -- but LDS 62 KB caps at
// 2 blocks/CU (16 waves), occupancy 38%, nothing saturated -> latency-bound.
// R13: LDS -> 52.5 KB (gates kb8 slab + B-zero frags moved to global ws) so
// 3 blocks/CU fit; launch_bounds(512,8) pins regs <=64 (natural 60) so the
// register file supports 24+ waves/CU. Grid 768 = 3 resident blocks/CU.
__global__ __launch_bounds__(512, 8)
void lstmdqn_v13(const float* __restrict__ xg,  const float* __restrict__ h0g,
                 const float* __restrict__ c0g,
                 const f16* __restrict__ ws,
                 const float* __restrict__ b1p, const float* __restrict__ b2p,
                 const float* __restrict__ b3p, const float* __restrict__ b4p,
                 const float* __restrict__ bhp,
                 float* __restrict__ out, int Bsz, int nt16) {
    __shared__ f16 sAB[128 * STR];    // 18.4 KB activations (8 waves x 16 rows)
    __shared__ f16 sWG[8 * 256 * 8];  // 32.8 KB gate Whh frags (kb0..7 only)
    __shared__ f16 sZL[512];          // 1 KB zero slab (A-side zero frags only)
    __shared__ float sBB[372];        // b1(256) | b2(64) | b3(32) | b4(16) | bh(3+pad)

    const int tid  = threadIdx.x;
    const int w    = tid >> 6, l = tid & 63;
    const int lrow = l & 15, hi = l >> 4;
    const int wrow = w * 16;

    // ---- stage gate Whh frags (straight 16B copy), biases, zero slab ----
    {
        const int4* src = (const int4*)(ws + OFF_WG);
        int4* dst = (int4*)sWG;
        for (int i = tid; i < 32768 / 8; i += 512) dst[i] = src[i];
    }
    for (int i = tid; i < 512; i += 512) sZL[i] = (f16)0.0f;
    if (tid < 256) sBB[tid] = b1p[tid];
    if (tid < 64)  sBB[256 + tid] = b2p[tid];
    if (tid < 32)  sBB[320 + tid] = b3p[tid];
    if (tid < 16)  sBB[352 + tid] = b4p[tid];
    if (tid < 3)   sBB[368 + tid] = bhp[tid];
    // permanent ABUF cols: 69 = 1.0 (bias feature), 70..71 = 0
    for (int i = tid; i < 128 * 3; i += 512) {
        int r = i / 3, c = 69 + (i - 3 * r);
        sAB[r * STR + c] = (f16)(c == 69 ? 1.0f : 0.0f);
    }
    __syncthreads();
    // ---- from here: each wave touches only its own 16 ABUF rows -> no barriers ----

    // tile-invariant per-lane pointers (LDS)
    const f16* pA  = &sAB[(wrow + lrow) * STR + hi * 8];
    const f16* pA2 = (hi == 0) ? &sAB[(wrow + lrow) * STR + 64] : &sZL[(l - 16) * 8];
    const f16* pWG = &sWG[(hi * 256 + lrow) * 8];
    // single write-base; q/col offsets are compile-time immediates (q*72 + col)
    const int rwb = (wrow + 4 * hi) * STR + lrow;

    #pragma unroll 1
    for (int tile = blockIdx.x * 8 + w; tile < nt16; tile += (gridDim.x << 3)) {
        const int rbase = tile * 16;

        // ---- anti-LICM: global weight-frag pointers made loop-variant (opaque) so
        //      their loads are NOT hoisted+spilled; they re-issue per tile from L2 ----
        uintptr_t uG2 = (uintptr_t)((hi == 0) ? (ws + OFF_WG + 16384 + lrow * 8)
                                              : (ws + OFF_Z + (l - 16) * 8));
        uintptr_t uW1 = (uintptr_t)(ws + OFF_W1 + (hi * 256 + lrow) * 8);
        uintptr_t uW2 = (uintptr_t)(ws + OFF_W2 + (hi * 64 + lrow) * 8);
        uintptr_t uW3 = (uintptr_t)(ws + OFF_W3 + (hi * 32 + lrow) * 8);
        uintptr_t uW4 = (uintptr_t)(ws + OFF_W4 + (hi * 16 + lrow) * 8);
        uintptr_t uWh = (uintptr_t)(ws + OFF_WH + (hi * 16 + lrow) * 8);
        asm volatile("" : "+v"(uG2), "+v"(uW1), "+v"(uW2), "+v"(uW3), "+v"(uW4), "+v"(uWh));
        const f16* gG2 = (const f16*)uG2;
        const f16* gW1 = (const f16*)uW1;
        const f16* gW2 = (const f16*)uW2;
        const f16* gW3 = (const f16*)uW3;
        const f16* gW4 = (const f16*)uW4;
        const f16* gWh = (const f16*)uWh;

        // ---- stage h0 (16 rows x 64) ----
        {
            const float* hp = h0g + (size_t)rbase * 64;
            #pragma unroll
            for (int e = 0; e < 4; ++e) {
                float4 v = *(const float4*)(hp + e * 256 + l * 4);
                int r = wrow + 4 * e + (l >> 4);
                int col = (4 * l) & 63;
                f16x4 hv = { (f16)v.x, (f16)v.y, (f16)v.z, (f16)v.w };
                *(f16x4*)&sAB[r * STR + col] = hv;
            }
        }
        // ---- c0 -> regs: creg[gq][q] = c[4hi+q][16gq+lrow] ----
        float creg[4][4];
        #pragma unroll
        for (int gq = 0; gq < 4; ++gq)
            #pragma unroll
            for (int q = 0; q < 4; ++q)
                creg[gq][q] = c0g[(size_t)(rbase + 4 * hi + q) * 64 + gq * 16 + lrow];

        // ---- 2 LSTM steps ----
        #pragma unroll
        for (int t = 0; t < 2; ++t) {
            if (l < 20) {  // stage x_t (16 rows x 5) into cols 64..68
                const float* xp = xg + (size_t)t * Bsz * 5 + (size_t)rbase * 5;
                float4 v = *(const float4*)(xp + 4 * l);
                float vv[4] = { v.x, v.y, v.z, v.w };
                #pragma unroll
                for (int e = 0; e < 4; ++e) {
                    int idx = 4 * l + e, r = idx / 5, ft = idx - 5 * r;
                    sAB[(wrow + r) * STR + 64 + ft] = (f16)vv[e];
                }
            }
            // A fragments (K=96)
            f16x8 af0 = *(const f16x8*)&pA[0];
            f16x8 af1 = *(const f16x8*)&pA[32];
            f16x8 af2 = *(const f16x8*)pA2;
            // 4 feature-quad phases: ct = gq + 4*gate -> i,f,g,o co-resident, ag live = 16
            #pragma unroll
            for (int gq = 0; gq < 4; ++gq) {
                f32x4 ag[4];
                #pragma unroll
                for (int g4 = 0; g4 < 4; ++g4) {
                    int ct = gq + 4 * g4;
                    f16x8 b0 = *(const f16x8*)&pWG[ct * 128];
                    f16x8 b1 = *(const f16x8*)&pWG[8192 + ct * 128];
                    f16x8 b2 = *(const f16x8*)&gG2[ct * 128];   // kb8 slab from L2
                    f32x4 a = { 0.f, 0.f, 0.f, 0.f };   // bias folded into k=69
                    a = MFMA(af0, b0, a);
                    a = MFMA(af1, b1, a);
                    a = MFMA(af2, b2, a);
                    ag[g4] = a;
                }
                #pragma unroll
                for (int q = 0; q < 4; ++q) {
                    float iv = sig2(ag[0][q]);
                    float fv = sig2(ag[1][q]);
                    float gv = 2.0f * sig2(ag[2][q]) - 1.0f;
                    float ov = sig2(ag[3][q]);
                    float c  = fv * creg[gq][q] + iv * gv;
                    creg[gq][q] = c;
                    float tc = 2.0f * sig2(L2E2 * c) - 1.0f;
                    float h  = ov * tc;
                    if (t == 1) h = fmaxf(h, 0.0f);
                    sAB[rwb + q * STR + gq * 16] = (f16)h;
                }
            }
        }

        // ---- z1 -> z2, fused per-ctl (a1 live = 4) ----
        f16x8 za0 = *(const f16x8*)&pA[0];
        f16x8 za1 = *(const f16x8*)&pA[32];
        f32x4 acc2[4];
        #pragma unroll
        for (int c2 = 0; c2 < 4; ++c2)
            acc2[c2] = (f32x4){ 0.f, 0.f, 0.f, 0.f };
        #pragma unroll
        for (int cc = 0; cc < 4; ++cc) {
            // each ctl: 2 MFMAs -> bias+relu -> write z1 slice immediately
            #pragma unroll
            for (int ctl = 0; ctl < 4; ++ctl) {
                int ct = cc * 4 + ctl;
                f16x8 b0 = *(const f16x8*)&gW1[ct * 128];
                f16x8 b1 = *(const f16x8*)&gW1[8192 + ct * 128];
                float bv = sBB[ct * 16 + lrow];
                f32x4 a = { 0.f, 0.f, 0.f, 0.f };
                a = MFMA(za0, b0, a);
                a = MFMA(za1, b1, a);
                #pragma unroll
                for (int q = 0; q < 4; ++q) {
                    float v = fmaxf(a[q] + bv, 0.0f);
                    sAB[rwb + q * STR + ctl * 16] = (f16)v;
                }
            }
            f16x8 ca0 = *(const f16x8*)&pA[0];
            f16x8 ca1 = *(const f16x8*)&pA[32];
            #pragma unroll
            for (int ct2 = 0; ct2 < 4; ++ct2) {
                f16x8 wb0 = *(const f16x8*)&gW2[cc * 4096 + ct2 * 128];
                f16x8 wb1 = *(const f16x8*)&gW2[cc * 4096 + 2048 + ct2 * 128];
                acc2[ct2] = MFMA(ca0, wb0, acc2[ct2]);
                acc2[ct2] = MFMA(ca1, wb1, acc2[ct2]);
            }
        }
        // write z2 (64 feats) to cols 0..63
        #pragma unroll
        for (int ct2 = 0; ct2 < 4; ++ct2) {
            float bv = sBB[256 + ct2 * 16 + lrow];
            #pragma unroll
            for (int q = 0; q < 4; ++q) {
                float v = fmaxf(acc2[ct2][q] + bv, 0.0f);
                sAB[rwb + q * STR + ct2 * 16] = (f16)v;
            }
        }
        // ---- z3: K=64, N=32 -> cols 0..31 ----
        {
            f16x8 a30 = *(const f16x8*)&pA[0];
            f16x8 a31 = *(const f16x8*)&pA[32];
            #pragma unroll
            for (int ctt = 0; ctt < 2; ++ctt) {
                f16x8 c0f = *(const f16x8*)&gW3[ctt * 128];
                f16x8 c1f = *(const f16x8*)&gW3[1024 + ctt * 128];
                float bv = sBB[320 + ctt * 16 + lrow];
                f32x4 a = { 0.f, 0.f, 0.f, 0.f };
                a = MFMA(a30, c0f, a);
                a = MFMA(a31, c1f, a);
                #pragma unroll
                for (int q = 0; q < 4; ++q) {
                    float v = fmaxf(a[q] + bv, 0.0f);
                    sAB[rwb + q * STR + ctt * 16] = (f16)v;
                }
            }
        }
        // ---- z4: K=32 (cols 0..31) -> cols 32..47 ----
        {
            f16x8 wb4 = *(const f16x8*)gW4;
            float bv = sBB[352 + lrow];
            f16x8 a4 = *(const f16x8*)&pA[0];
            f32x4 a = { 0.f, 0.f, 0.f, 0.f };
            a = MFMA(a4, wb4, a);
            #pragma unroll
            for (int q = 0; q < 4; ++q) {
                float v = fmaxf(a[q] + bv, 0.0f);
                sAB[rwb + q * STR + 32] = (f16)v;
            }
        }
        // ---- head: K=32 over cols 32..63 (48..63 stale x zero weights) ----
        {
            f16x8 wbh = *(const f16x8*)gWh;
            f16x8 ah = *(const f16x8*)&pA[32];
            f32x4 a = { 0.f, 0.f, 0.f, 0.f };
            a = MFMA(ah, wbh, a);
            if (lrow < 3) {
                float bv = sBB[368 + lrow];
                #pragma unroll
                for (int q = 0; q < 4; ++q)
                    out[(size_t)(rbase + 4 * hi + q) * 3 + lrow] = a[q] + bv;
            }
        }
    }
}

extern "C" void kernel_launch(void* const* d_in, const int* in_sizes, int n_in,
                              void* d_out, int out_size, void* d_ws, size_t ws_size,
                              hipStream_t stream) {
    const float* x   = (const float*)d_in[0];
    const float* h0  = (const float*)d_in[1];
    const float* c0  = (const float*)d_in[2];
    const float* Wih = (const float*)d_in[3];
    const float* Whh = (const float*)d_in[4];
    const float* bih = (const float*)d_in[5];
    const float* bhh = (const float*)d_in[6];
    const float* w1  = (const float*)d_in[7];
    const float* b1  = (const float*)d_in[8];
    const float* w2  = (const float*)d_in[9];
    const float* b2  = (const float*)d_in[10];
    const float* w3  = (const float*)d_in[11];
    const float* b3  = (const float*)d_in[12];
    const float* w4  = (const float*)d_in[13];
    const float* b4  = (const float*)d_in[14];
    const float* wh  = (const float*)d_in[15];
    const float* bh  = (const float*)d_in[16];

    int Bsz  = in_sizes[1] / 64;   // h0 is [B, 64]
    int nt16 = Bsz / 16;           // 16-row tiles

    f16* ws = (f16*)d_ws;
    wprep<<<(WS_TOT + 255) / 256, 256, 0, stream>>>(Wih, Whh, bih, bhh,
                                                    w1, w2, w3, w4, wh, ws);
    // 768 blocks = 3 blocks/CU (52.5 KB LDS each); 8 waves x 16 rows; ~2.7 tiles/wave
    lstmdqn_v13<<<768, 512, 0, stream>>>(x, h0, c0, ws, b1, b2, b3, b4, bh,
                                         (float*)d_out, Bsz, nt16);
}

// Round 14
// 85.714 us; speedup vs baseline: 1.2054x; 1.2054x over previous
//
#include <hip/hip_runtime.h>

typedef _Float16 f16;
typedef _Float16 f16x4 __attribute__((ext_vector_type(4)));
typedef _Float16 f16x8 __attribute__((ext_vector_type(8)));
typedef float    f32x4 __attribute__((ext_vector_type(4)));

#define MFMA(A,B,C) __builtin_amdgcn_mfma_f32_16x16x32_f16((A),(B),(C),0,0,0)

// sigmoid on pre-scaled input y = x*log2(e): 1/(1+2^-y)
__device__ __forceinline__ float sig2(float y) {
    return __builtin_amdgcn_rcpf(1.0f + __builtin_amdgcn_exp2f(-y));
}

constexpr float L2E  = 1.4426950408889634f;
constexpr float L2E2 = 2.8853900817779268f;

constexpr int STR = 72;   // ABUF row stride (f16): cols 0..63 act | 64..68 x | 69 = 1.0 | 70..71 = 0

// d_ws fragment-layout offsets (f16 elems); all [kt][n][8] with elem = (kt*N + n)*8 + j
constexpr int OFF_WG = 0;          // [9][256][8]  gates (prescaled, bias at k=69)
constexpr int OFF_W1 = 18432;      // [8][256][8]
constexpr int OFF_W2 = 34816;      // [32][64][8]
constexpr int OFF_W3 = 51200;      // [8][32][8]
constexpr int OFF_W4 = 53248;      // [4][16][8]
constexpr int OFF_WH = 53760;      // [4][16][8] (zero-padded k>=16, n>=3)
constexpr int WS_TOT = 54272;

// ---------------- prep kernel: build f16 fragment buffers in d_ws ----------------
__global__ void wprep(const float* __restrict__ Wih, const float* __restrict__ Whh,
                      const float* __restrict__ bih, const float* __restrict__ bhh,
                      const float* __restrict__ w1p, const float* __restrict__ w2p,
                      const float* __restrict__ w3p, const float* __restrict__ w4p,
                      const float* __restrict__ whp, f16* __restrict__ ws) {
    int idx = blockIdx.x * 256 + threadIdx.x;
    if (idx >= WS_TOT) return;
    float v = 0.0f;
    if (idx < OFF_W1) {                       // gates, prescaled by L2E (i,f,o) / 2*L2E (g)
        int r = idx, kb = r >> 11, n = (r >> 3) & 255, j = r & 7;
        float sc = (n >= 128 && n < 192) ? L2E2 : L2E;
        if (kb < 8)      v = Whh[n * 64 + kb * 8 + j];
        else if (j < 5)  v = Wih[n * 5 + j];
        else if (j == 5) v = bih[n] + bhh[n];
        v *= sc;
    } else if (idx < OFF_W2) {
        int r = idx - OFF_W1, kt = r >> 11, n = (r >> 3) & 255, j = r & 7;
        v = w1p[n * 64 + kt * 8 + j];
    } else if (idx < OFF_W3) {
        int r = idx - OFF_W2, kt = r >> 9, n = (r >> 3) & 63, j = r & 7;
        v = w2p[n * 256 + kt * 8 + j];
    } else if (idx < OFF_W4) {
        int r = idx - OFF_W3, kt = r >> 8, n = (r >> 3) & 31, j = r & 7;
        v = w3p[n * 64 + kt * 8 + j];
    } else if (idx < OFF_WH) {
        int r = idx - OFF_W4, kt = r >> 7, n = (r >> 3) & 15, j = r & 7;
        v = w4p[n * 32 + kt * 8 + j];
    } else {
        int r = idx - OFF_WH, kt = r >> 7, n = (r >> 3) & 15, j = r & 7;
        int k = kt * 8 + j;
        v = (k < 16 && n < 3) ? whp[n * 16 + k] : 0.0f;
    }
    ws[idx] = (f16)v;
}

// ---------------- main kernel ----------------
// R12 (best, 86us): 16-row tiles, no spill, occ ~38% (cap appears to be total
// VGPR+AGPR, not LDS -- R13 proved LDS shaving doesn't raise it, and the L2
// gates path regressed). R14: keep R12's memory layout; apply async-stage split
// (T14): x0+x1 loaded at tile start (x1 LDS-write placed after t0's af2 read);
// next tile's h0/x loads issued before z1, written at next loop top. Removes
// both global-load stalls from the per-tile critical chain. +24 regs held
// through z-phases: peak ~119 < 128 budget -> no spill expected.
__global__ __launch_bounds__(512, 4)
void lstmdqn_v14(const float* __restrict__ xg,  const float* __restrict__ h0g,
                 const float* __restrict__ c0g,
                 const f16* __restrict__ ws,
                 const float* __restrict__ b1p, const float* __restrict__ b2p,
                 const float* __restrict__ b3p, const float* __restrict__ b4p,
                 const float* __restrict__ bhp,
                 float* __restrict__ out, int Bsz, int nt16) {
    __shared__ f16 sAB[128 * STR];    // 18.4 KB activations (8 waves x 16 rows)
    __shared__ f16 sWG[9 * 256 * 8];  // 36.9 KB gate weight frags (copied from ws)
    __shared__ f16 sZL[2560];         // 5 KB zero slab
    __shared__ float sBB[372];        // b1(256) | b2(64) | b3(32) | b4(16) | bh(3+pad)

    const int tid  = threadIdx.x;
    const int w    = tid >> 6, l = tid & 63;
    const int lrow = l & 15, hi = l >> 4;
    const int wrow = w * 16;

    // ---- stage gate frags (straight 16B copy), biases, zero slab ----
    {
        const int4* src = (const int4*)(ws + OFF_WG);
        int4* dst = (int4*)sWG;
        for (int i = tid; i < 18432 / 8; i += 512) dst[i] = src[i];
    }
    for (int i = tid; i < 2560; i += 512) sZL[i] = (f16)0.0f;
    if (tid < 256) sBB[tid] = b1p[tid];
    if (tid < 64)  sBB[256 + tid] = b2p[tid];
    if (tid < 32)  sBB[320 + tid] = b3p[tid];
    if (tid < 16)  sBB[352 + tid] = b4p[tid];
    if (tid < 3)   sBB[368 + tid] = bhp[tid];
    // permanent ABUF cols: 69 = 1.0 (bias feature), 70..71 = 0
    for (int i = tid; i < 128 * 3; i += 512) {
        int r = i / 3, c = 69 + (i - 3 * r);
        sAB[r * STR + c] = (f16)(c == 69 ? 1.0f : 0.0f);
    }
    __syncthreads();
    // ---- from here: each wave touches only its own 16 ABUF rows -> no barriers ----

    // tile-invariant per-lane pointers (LDS)
    const f16* pA  = &sAB[(wrow + lrow) * STR + hi * 8];
    const f16* pA2 = (hi == 0) ? &sAB[(wrow + lrow) * STR + 64] : &sZL[l * 8];
    const f16* pWG  = &sWG[(hi * 256 + lrow) * 8];
    const f16* pWG2 = (hi == 0) ? &sWG[8 * 2048 + lrow * 8] : &sZL[l * 8];
    // single write-base; q/col offsets are compile-time immediates (q*72 + col)
    const int rwb = (wrow + 4 * hi) * STR + lrow;

    // ---- prologue prefetch for first tile (T14 issue-early) ----
    float4 hpre0 = {0,0,0,0}, hpre1 = {0,0,0,0}, hpre2 = {0,0,0,0}, hpre3 = {0,0,0,0};
    float4 x0pre = {0,0,0,0}, x1pre = {0,0,0,0};
    {
        int t0 = blockIdx.x * 8 + w;
        if (t0 < nt16) {
            const float* hp = h0g + (size_t)t0 * 16 * 64;
            hpre0 = *(const float4*)(hp + 0 * 256 + l * 4);
            hpre1 = *(const float4*)(hp + 1 * 256 + l * 4);
            hpre2 = *(const float4*)(hp + 2 * 256 + l * 4);
            hpre3 = *(const float4*)(hp + 3 * 256 + l * 4);
            if (l < 20) {
                x0pre = *(const float4*)(xg + (size_t)t0 * 80 + 4 * l);
                x1pre = *(const float4*)(xg + (size_t)Bsz * 5 + (size_t)t0 * 80 + 4 * l);
            }
        }
    }

    #pragma unroll 1
    for (int tile = blockIdx.x * 8 + w; tile < nt16; tile += (gridDim.x << 3)) {
        const int rbase = tile * 16;

        // ---- anti-LICM: weight-frag pointers made loop-variant (opaque) so their
        //      loads are NOT hoisted+spilled; they re-issue per tile from L2 ----
        uintptr_t uW1 = (uintptr_t)(ws + OFF_W1 + (hi * 256 + lrow) * 8);
        uintptr_t uW2 = (uintptr_t)(ws + OFF_W2 + (hi * 64 + lrow) * 8);
        uintptr_t uW3 = (uintptr_t)(ws + OFF_W3 + (hi * 32 + lrow) * 8);
        uintptr_t uW4 = (uintptr_t)(ws + OFF_W4 + (hi * 16 + lrow) * 8);
        uintptr_t uWh = (uintptr_t)(ws + OFF_WH + (hi * 16 + lrow) * 8);
        asm volatile("" : "+v"(uW1), "+v"(uW2), "+v"(uW3), "+v"(uW4), "+v"(uWh));
        const f16* gW1 = (const f16*)uW1;
        const f16* gW2 = (const f16*)uW2;
        const f16* gW3 = (const f16*)uW3;
        const f16* gW4 = (const f16*)uW4;
        const f16* gWh = (const f16*)uWh;

        // ---- stage h0 (16 rows x 64) from PREFETCHED regs (write-late half of T14) ----
        {
            int r0 = wrow + (l >> 4);
            int col = (4 * l) & 63;
            f16x4 h0v = { (f16)hpre0.x, (f16)hpre0.y, (f16)hpre0.z, (f16)hpre0.w };
            f16x4 h1v = { (f16)hpre1.x, (f16)hpre1.y, (f16)hpre1.z, (f16)hpre1.w };
            f16x4 h2v = { (f16)hpre2.x, (f16)hpre2.y, (f16)hpre2.z, (f16)hpre2.w };
            f16x4 h3v = { (f16)hpre3.x, (f16)hpre3.y, (f16)hpre3.z, (f16)hpre3.w };
            *(f16x4*)&sAB[(r0 +  0) * STR + col] = h0v;
            *(f16x4*)&sAB[(r0 +  4) * STR + col] = h1v;
            *(f16x4*)&sAB[(r0 +  8) * STR + col] = h2v;
            *(f16x4*)&sAB[(r0 + 12) * STR + col] = h3v;
        }
        // ---- stage x0 from prefetched regs ----
        if (l < 20) {
            float vv[4] = { x0pre.x, x0pre.y, x0pre.z, x0pre.w };
            #pragma unroll
            for (int e = 0; e < 4; ++e) {
                int idx = 4 * l + e, r = idx / 5, ft = idx - 5 * r;
                sAB[(wrow + r) * STR + 64 + ft] = (f16)vv[e];
            }
        }
        // ---- c0 -> regs: creg[gq][q] = c[4hi+q][16gq+lrow] ----
        float creg[4][4];
        #pragma unroll
        for (int gq = 0; gq < 4; ++gq)
            #pragma unroll
            for (int q = 0; q < 4; ++q)
                creg[gq][q] = c0g[(size_t)(rbase + 4 * hi + q) * 64 + gq * 16 + lrow];

        // ---- 2 LSTM steps ----
        #pragma unroll
        for (int t = 0; t < 2; ++t) {
            // A fragments (K=96)
            f16x8 af0 = *(const f16x8*)&pA[0];
            f16x8 af1 = *(const f16x8*)&pA[32];
            f16x8 af2 = *(const f16x8*)pA2;
            // after t0's af2 READ (wave program order), stage x1 for t=1 -- no
            // global latency here, x1 was loaded at tile start
            if (t == 0 && l < 20) {
                float vv[4] = { x1pre.x, x1pre.y, x1pre.z, x1pre.w };
                #pragma unroll
                for (int e = 0; e < 4; ++e) {
                    int idx = 4 * l + e, r = idx / 5, ft = idx - 5 * r;
                    sAB[(wrow + r) * STR + 64 + ft] = (f16)vv[e];
                }
            }
            // 4 feature-quad phases: ct = gq + 4*gate -> i,f,g,o co-resident, ag live = 16
            #pragma unroll
            for (int gq = 0; gq < 4; ++gq) {
                f32x4 ag[4];
                #pragma unroll
                for (int g4 = 0; g4 < 4; ++g4) {
                    int ct = gq + 4 * g4;
                    f16x8 b0 = *(const f16x8*)&pWG[ct * 128];
                    f16x8 b1 = *(const f16x8*)&pWG[8192 + ct * 128];
                    f16x8 b2 = *(const f16x8*)&pWG2[ct * 128];
                    f32x4 a = { 0.f, 0.f, 0.f, 0.f };   // bias folded into k=69
                    a = MFMA(af0, b0, a);
                    a = MFMA(af1, b1, a);
                    a = MFMA(af2, b2, a);
                    ag[g4] = a;
                }
                #pragma unroll
                for (int q = 0; q < 4; ++q) {
                    float iv = sig2(ag[0][q]);
                    float fv = sig2(ag[1][q]);
                    float gv = 2.0f * sig2(ag[2][q]) - 1.0f;
                    float ov = sig2(ag[3][q]);
                    float c  = fv * creg[gq][q] + iv * gv;
                    creg[gq][q] = c;
                    float tc = 2.0f * sig2(L2E2 * c) - 1.0f;
                    float h  = ov * tc;
                    if (t == 1) h = fmaxf(h, 0.0f);
                    sAB[rwb + q * STR + gq * 16] = (f16)h;
                }
            }
        }

        // ---- prefetch next tile's h0/x (issue-early half of T14): latency hides
        //      under the z-layer compute below; regs written at next loop top ----
        {
            int nxt = tile + (gridDim.x << 3);
            if (nxt < nt16) {
                const float* hp = h0g + (size_t)nxt * 16 * 64;
                hpre0 = *(const float4*)(hp + 0 * 256 + l * 4);
                hpre1 = *(const float4*)(hp + 1 * 256 + l * 4);
                hpre2 = *(const float4*)(hp + 2 * 256 + l * 4);
                hpre3 = *(const float4*)(hp + 3 * 256 + l * 4);
                if (l < 20) {
                    x0pre = *(const float4*)(xg + (size_t)nxt * 80 + 4 * l);
                    x1pre = *(const float4*)(xg + (size_t)Bsz * 5 + (size_t)nxt * 80 + 4 * l);
                }
            }
        }

        // ---- z1 -> z2, fused per-ctl (a1 live = 4) ----
        f16x8 za0 = *(const f16x8*)&pA[0];
        f16x8 za1 = *(const f16x8*)&pA[32];
        f32x4 acc2[4];
        #pragma unroll
        for (int c2 = 0; c2 < 4; ++c2)
            acc2[c2] = (f32x4){ 0.f, 0.f, 0.f, 0.f };
        #pragma unroll
        for (int cc = 0; cc < 4; ++cc) {
            // each ctl: 2 MFMAs -> bias+relu -> write z1 slice immediately
            #pragma unroll
            for (int ctl = 0; ctl < 4; ++ctl) {
                int ct = cc * 4 + ctl;
                f16x8 b0 = *(const f16x8*)&gW1[ct * 128];
                f16x8 b1 = *(const f16x8*)&gW1[8192 + ct * 128];
                float bv = sBB[ct * 16 + lrow];
                f32x4 a = { 0.f, 0.f, 0.f, 0.f };
                a = MFMA(za0, b0, a);
                a = MFMA(za1, b1, a);
                #pragma unroll
                for (int q = 0; q < 4; ++q) {
                    float v = fmaxf(a[q] + bv, 0.0f);
                    sAB[rwb + q * STR + ctl * 16] = (f16)v;
                }
            }
            f16x8 ca0 = *(const f16x8*)&pA[0];
            f16x8 ca1 = *(const f16x8*)&pA[32];
            #pragma unroll
            for (int ct2 = 0; ct2 < 4; ++ct2) {
                f16x8 wb0 = *(const f16x8*)&gW2[cc * 4096 + ct2 * 128];
                f16x8 wb1 = *(const f16x8*)&gW2[cc * 4096 + 2048 + ct2 * 128];
                acc2[ct2] = MFMA(ca0, wb0, acc2[ct2]);
                acc2[ct2] = MFMA(ca1, wb1, acc2[ct2]);
            }
        }
        // write z2 (64 feats) to cols 0..63
        #pragma unroll
        for (int ct2 = 0; ct2 < 4; ++ct2) {
            float bv = sBB[256 + ct2 * 16 + lrow];
            #pragma unroll
            for (int q = 0; q < 4; ++q) {
                float v = fmaxf(acc2[ct2][q] + bv, 0.0f);
                sAB[rwb + q * STR + ct2 * 16] = (f16)v;
            }
        }
        // ---- z3: K=64, N=32 -> cols 0..31 ----
        {
            f16x8 a30 = *(const f16x8*)&pA[0];
            f16x8 a31 = *(const f16x8*)&pA[32];
            #pragma unroll
            for (int ctt = 0; ctt < 2; ++ctt) {
                f16x8 c0f = *(const f16x8*)&gW3[ctt * 128];
                f16x8 c1f = *(const f16x8*)&gW3[1024 + ctt * 128];
                float bv = sBB[320 + ctt * 16 + lrow];
                f32x4 a = { 0.f, 0.f, 0.f, 0.f };
                a = MFMA(a30, c0f, a);
                a = MFMA(a31, c1f, a);
                #pragma unroll
                for (int q = 0; q < 4; ++q) {
                    float v = fmaxf(a[q] + bv, 0.0f);
                    sAB[rwb + q * STR + ctt * 16] = (f16)v;
                }
            }
        }
        // ---- z4: K=32 (cols 0..31) -> cols 32..47 ----
        {
            f16x8 wb4 = *(const f16x8*)gW4;
            float bv = sBB[352 + lrow];
            f16x8 a4 = *(const f16x8*)&pA[0];
            f32x4 a = { 0.f, 0.f, 0.f, 0.f };
            a = MFMA(a4, wb4, a);
            #pragma unroll
            for (int q = 0; q < 4; ++q) {
                float v = fmaxf(a[q] + bv, 0.0f);
                sAB[rwb + q * STR + 32] = (f16)v;
            }
        }
        // ---- head: K=32 over cols 32..63 (48..63 stale x zero weights) ----
        {
            f16x8 wbh = *(const f16x8*)gWh;
            f16x8 ah = *(const f16x8*)&pA[32];
            f32x4 a = { 0.f, 0.f, 0.f, 0.f };
            a = MFMA(ah, wbh, a);
            if (lrow < 3) {
                float bv = sBB[368 + lrow];
                #pragma unroll
                for (int q = 0; q < 4; ++q)
                    out[(size_t)(rbase + 4 * hi + q) * 3 + lrow] = a[q] + bv;
            }
        }
    }
}

extern "C" void kernel_launch(void* const* d_in, const int* in_sizes, int n_in,
                              void* d_out, int out_size, void* d_ws, size_t ws_size,
                              hipStream_t stream) {
    const float* x   = (const float*)d_in[0];
    const float* h0  = (const float*)d_in[1];
    const float* c0  = (const float*)d_in[2];
    const float* Wih = (const float*)d_in[3];
    const float* Whh = (const float*)d_in[4];
    const float* bih = (const float*)d_in[5];
    const float* bhh = (const float*)d_in[6];
    const float* w1  = (const float*)d_in[7];
    const float* b1  = (const float*)d_in[8];
    const float* w2  = (const float*)d_in[9];
    const float* b2  = (const float*)d_in[10];
    const float* w3  = (const float*)d_in[11];
    const float* b3  = (const float*)d_in[12];
    const float* w4  = (const float*)d_in[13];
    const float* b4  = (const float*)d_in[14];
    const float* wh  = (const float*)d_in[15];
    const float* bh  = (const float*)d_in[16];

    int Bsz  = in_sizes[1] / 64;   // h0 is [B, 64]
    int nt16 = Bsz / 16;           // 16-row tiles

    f16* ws = (f16*)d_ws;
    wprep<<<(WS_TOT + 255) / 256, 256, 0, stream>>>(Wih, Whh, bih, bhh,
                                                    w1, w2, w3, w4, wh, ws);
    // 512 blocks = 2 blocks/CU (62 KB LDS each); 8 waves x 16 rows; 4 tiles/wave
    lstmdqn_v14<<<512, 512, 0, stream>>>(x, h0, c0, ws, b1, b2, b3, b4, bh,
                                         (float*)d_out, Bsz, nt16);
}